// Round 4
// baseline (2022.278 us; speedup 1.0000x reference)
//
#include <hip/hip_runtime.h>
#include <math.h>

// Problem constants (fixed by the reference).
#define NROWS 12288

__device__ __forceinline__ float elu_f(float x) { return x > 0.f ? x : expm1f(x); }

// ---------------------------------------------------------------------------
// enc1: out[m,0:32] = elu(concat(one_hot[m,0:20], features[m,0:44]) @ We1 + be1)
// ---------------------------------------------------------------------------
__global__ __launch_bounds__(256) void enc1_kernel(
    const float* __restrict__ oh, const float* __restrict__ ft,
    const float* __restrict__ W, const float* __restrict__ b,
    float* __restrict__ out)
{
    int id = blockIdx.x * 256 + threadIdx.x;
    if (id >= NROWS * 8) return;
    int o4 = id & 7;
    int m  = id >> 3;
    const float4* W4 = reinterpret_cast<const float4*>(W);
    float4 acc = reinterpret_cast<const float4*>(b)[o4];
    const float* ohr = oh + m * 20;
    const float* ftr = ft + m * 44;
#pragma unroll
    for (int i = 0; i < 64; ++i) {
        float x = (i < 20) ? ohr[i] : ftr[i - 20];
        float4 w = W4[i * 8 + o4];
        acc.x = fmaf(x, w.x, acc.x);
        acc.y = fmaf(x, w.y, acc.y);
        acc.z = fmaf(x, w.z, acc.z);
        acc.w = fmaf(x, w.w, acc.w);
    }
    acc.x = elu_f(acc.x); acc.y = elu_f(acc.y);
    acc.z = elu_f(acc.z); acc.w = elu_f(acc.w);
    reinterpret_cast<float4*>(out)[id] = acc;
}

// ---------------------------------------------------------------------------
// Generic dense linear (small weights), one thread per float4 of output.
// ---------------------------------------------------------------------------
template <int IN, int OUT, bool BIAS, bool ACT_ELU>
__global__ __launch_bounds__(256) void linear4_kernel(
    const float* __restrict__ in, const float* __restrict__ W,
    const float* __restrict__ b, float* __restrict__ out)
{
    constexpr int O4 = OUT / 4;
    int id = blockIdx.x * 256 + threadIdx.x;
    if (id >= NROWS * O4) return;
    int o4 = id % O4;
    int m  = id / O4;
    float4 acc;
    if (BIAS) acc = reinterpret_cast<const float4*>(b)[o4];
    else      acc = make_float4(0.f, 0.f, 0.f, 0.f);
    const float*  ip = in + (size_t)m * IN;
    const float4* W4 = reinterpret_cast<const float4*>(W);
#pragma unroll 8
    for (int i = 0; i < IN; ++i) {
        float  x = ip[i];
        float4 w = W4[i * O4 + o4];
        acc.x = fmaf(x, w.x, acc.x);
        acc.y = fmaf(x, w.y, acc.y);
        acc.z = fmaf(x, w.z, acc.z);
        acc.w = fmaf(x, w.w, acc.w);
    }
    if (ACT_ELU) {
        acc.x = elu_f(acc.x); acc.y = elu_f(acc.y);
        acc.z = elu_f(acc.z); acc.w = elu_f(acc.w);
    }
    reinterpret_cast<float4*>(out)[id] = acc;
}

// ---------------------------------------------------------------------------
// Aggregation: part[seg][m, o] = sum_{k in seg} A[m,k] * h[k,o]
//
// LDS-traffic-minimized fp32 GEMM (round-1 was LDS-pipe-bound at 1.6 TB/s):
//  - 256 threads as TROWS row-groups x TCOLS cols; TM=8 rows/thread.
//    TCOLS (=8) threads share a row-group -> A-fragment LDS reads are
//    lane-BROADCAST (unique data ~512B/wave/k instead of 3KB).
//  - A staged transposed At[k][m ^ (k&28)]: XOR swizzle makes the scalar
//    transpose-writes 2-way-conflict (free) instead of 8-way.
//  - Next tile's global loads issued into registers BEFORE compute phase
//    (prefetch; HBM latency hides under FMA).
//  - Split-K (16 segments) for occupancy; disjoint partial slabs, no atomics.
// ---------------------------------------------------------------------------
template <int OUT, int TM, int TN>
__global__ __launch_bounds__(256, 3) void agg_kernel(
    const float* __restrict__ A, const float* __restrict__ h,
    float* __restrict__ part)
{
    constexpr int BK = 32, BM = 256, SPLIT = 16;
    constexpr int TCOLS = OUT / TN;
    constexpr int TROWS = 256 / TCOLS;
    static_assert(TROWS * TM == BM, "tile mismatch");
    constexpr int MT  = NROWS / BM;        // 48
    constexpr int SEG = NROWS / SPLIT;     // 768
    constexpr int NT  = SEG / BK;          // 24
    constexpr int HV  = BK * OUT / 4;      // float4s in h tile
    constexpr int HL  = (HV + 255) / 256;

    __shared__ float At[BK][BM];           // transposed + XOR-swizzled
    __shared__ float Hs[BK][OUT];

    const int tid = threadIdx.x;
    const int mt  = blockIdx.x % MT;
    const int seg = blockIdx.x / MT;
    const int m0  = mt * BM;
    const int kb  = seg * SEG;

    const int r0 = tid >> 3;               // 0..31 row within load pass
    const int c4 = tid & 7;                // 0..7  k-chunk (4 floats)
    const int tcol = tid % TCOLS;
    const int trow = tid / TCOLS;

    const float* Abase = A + (size_t)(m0 + r0) * NROWS + c4 * 4;

    float4 av[8];
    float4 hv[HL];

    auto load_tile = [&](int k0) {
#pragma unroll
        for (int p = 0; p < 8; ++p)
            av[p] = *reinterpret_cast<const float4*>(Abase + (size_t)(p * 32) * NROWS + k0);
        const float4* hsrc = reinterpret_cast<const float4*>(h + (size_t)k0 * OUT);
#pragma unroll
        for (int i = 0; i < HL; ++i)
            if (HV >= 256 * (i + 1) || i * 256 + tid < HV) hv[i] = hsrc[i * 256 + tid];
    };

    float acc[TM][TN];
#pragma unroll
    for (int i = 0; i < TM; ++i)
#pragma unroll
        for (int j = 0; j < TN; ++j) acc[i][j] = 0.f;

    load_tile(kb);

    for (int t = 0; t < NT; ++t) {
        __syncthreads();                   // previous tile's LDS reads done
        // ---- store A transposed+swizzled: At[kk][m ^ (kk&28)], kk = c4*4+j
        const int sw = c4 * 4;             // == (kk & 28) for this thread's 4 kk
#pragma unroll
        for (int p = 0; p < 8; ++p) {
            const int md = (r0 + p * 32) ^ sw;
            At[sw + 0][md] = av[p].x;
            At[sw + 1][md] = av[p].y;
            At[sw + 2][md] = av[p].z;
            At[sw + 3][md] = av[p].w;
        }
        float4* hdst = reinterpret_cast<float4*>(&Hs[0][0]);
#pragma unroll
        for (int i = 0; i < HL; ++i)
            if (HV >= 256 * (i + 1) || i * 256 + tid < HV) hdst[i * 256 + tid] = hv[i];
        __syncthreads();                   // tile visible

        if (t + 1 < NT) load_tile(kb + (t + 1) * BK);   // prefetch under compute

        // ---- inner product; kk compile-time (full unroll) so swizzle folds
#pragma unroll
        for (int kk = 0; kk < BK; ++kk) {
            const int s24 = kk & 24, s4 = kk & 4;
            float af[TM];
            if constexpr (TM == 8) {
                const int base8 = (trow * 8) ^ s24;
                float4 a0 = *reinterpret_cast<const float4*>(&At[kk][base8 + s4]);
                float4 a1 = *reinterpret_cast<const float4*>(&At[kk][base8 + (s4 ^ 4)]);
                af[0] = a0.x; af[1] = a0.y; af[2] = a0.z; af[3] = a0.w;
                af[4] = a1.x; af[5] = a1.y; af[6] = a1.z; af[7] = a1.w;
            } else {                       // TM == 4
                const int b4 = (trow * 4) ^ (s24 | s4);
                float4 a0 = *reinterpret_cast<const float4*>(&At[kk][b4]);
                af[0] = a0.x; af[1] = a0.y; af[2] = a0.z; af[3] = a0.w;
            }
            float hf[TN];
            if constexpr (TN == 8) {
                float4 b0 = *reinterpret_cast<const float4*>(&Hs[kk][tcol * 8]);
                float4 b1 = *reinterpret_cast<const float4*>(&Hs[kk][tcol * 8 + 4]);
                hf[0] = b0.x; hf[1] = b0.y; hf[2] = b0.z; hf[3] = b0.w;
                hf[4] = b1.x; hf[5] = b1.y; hf[6] = b1.z; hf[7] = b1.w;
            } else if constexpr (TN == 4) {
                float4 b0 = *reinterpret_cast<const float4*>(&Hs[kk][tcol * 4]);
                hf[0] = b0.x; hf[1] = b0.y; hf[2] = b0.z; hf[3] = b0.w;
            } else if constexpr (TN == 2) {
                float2 b0 = *reinterpret_cast<const float2*>(&Hs[kk][tcol * 2]);
                hf[0] = b0.x; hf[1] = b0.y;
            } else {
                hf[0] = Hs[kk][tcol];
            }
#pragma unroll
            for (int i = 0; i < TM; ++i)
#pragma unroll
                for (int j = 0; j < TN; ++j)
                    acc[i][j] = fmaf(af[i], hf[j], acc[i][j]);
        }
    }

    // ---- write partials (exclusive region per block)
    float* pd = part + (size_t)seg * ((size_t)NROWS * OUT);
#pragma unroll
    for (int i = 0; i < TM; ++i) {
        const int m = m0 + trow * TM + i;
        float* row = pd + (size_t)m * OUT + tcol * TN;
        if constexpr (TN == 8) {
            *reinterpret_cast<float4*>(row)     = make_float4(acc[i][0], acc[i][1], acc[i][2], acc[i][3]);
            *reinterpret_cast<float4*>(row + 4) = make_float4(acc[i][4], acc[i][5], acc[i][6], acc[i][7]);
        } else if constexpr (TN == 4) {
            *reinterpret_cast<float4*>(row) = make_float4(acc[i][0], acc[i][1], acc[i][2], acc[i][3]);
        } else if constexpr (TN == 2) {
            *reinterpret_cast<float2*>(row) = make_float2(acc[i][0], acc[i][1]);
        } else {
            row[0] = acc[i][0];
        }
    }
}

// ---------------------------------------------------------------------------
// Reduce split-K partials, add bias, ELU -> next x.
// ---------------------------------------------------------------------------
template <int OUT, int SPLIT>
__global__ __launch_bounds__(256) void reduce_kernel(
    const float* __restrict__ part, const float* __restrict__ b,
    float* __restrict__ out)
{
    constexpr int O4 = OUT / 4;
    int id = blockIdx.x * 256 + threadIdx.x;
    if (id >= NROWS * O4) return;
    const float4* p4 = reinterpret_cast<const float4*>(part);
    float4 s = p4[id];
#pragma unroll
    for (int t = 1; t < SPLIT; ++t) {
        float4 v = p4[(size_t)t * (NROWS * O4) + id];
        s.x += v.x; s.y += v.y; s.z += v.z; s.w += v.w;
    }
    float4 bb = reinterpret_cast<const float4*>(b)[id % O4];
    s.x = elu_f(s.x + bb.x); s.y = elu_f(s.y + bb.y);
    s.z = elu_f(s.z + bb.z); s.w = elu_f(s.w + bb.w);
    reinterpret_cast<float4*>(out)[id] = s;
}

// ---------------------------------------------------------------------------
// Layer-5 reduce fused with the whole final MLP + sigmoid. One thread per row.
// ---------------------------------------------------------------------------
__global__ __launch_bounds__(256) void reduce5_final_kernel(
    const float* __restrict__ part, const float* __restrict__ bg,
    const float* __restrict__ Wf1, const float* __restrict__ bf1,
    const float* __restrict__ Wf2, const float* __restrict__ bf2,
    const float* __restrict__ Wf3, const float* __restrict__ bf3,
    float* __restrict__ out)
{
    int m = blockIdx.x * 256 + threadIdx.x;
    if (m >= NROWS) return;
    const float4* p4 = reinterpret_cast<const float4*>(part);
    float4 s = p4[m];
#pragma unroll
    for (int t = 1; t < 16; ++t) {
        float4 v = p4[(size_t)t * NROWS + m];
        s.x += v.x; s.y += v.y; s.z += v.z; s.w += v.w;
    }
    float x0 = elu_f(s.x + bg[0]);
    float x1 = elu_f(s.y + bg[1]);
    float x2 = elu_f(s.z + bg[2]);
    float x3 = elu_f(s.w + bg[3]);

    float t1[8];
#pragma unroll
    for (int o = 0; o < 8; ++o) {
        float a = bf1[o];
        a = fmaf(x0, Wf1[0 * 8 + o], a);
        a = fmaf(x1, Wf1[1 * 8 + o], a);
        a = fmaf(x2, Wf1[2 * 8 + o], a);
        a = fmaf(x3, Wf1[3 * 8 + o], a);
        t1[o] = elu_f(a);
    }
    float t2[4];
#pragma unroll
    for (int o = 0; o < 4; ++o) {
        float a = bf2[o];
#pragma unroll
        for (int i = 0; i < 8; ++i) a = fmaf(t1[i], Wf2[i * 4 + o], a);
        t2[o] = elu_f(a);
    }
    float z = bf3[0];
#pragma unroll
    for (int i = 0; i < 4; ++i) z = fmaf(t2[i], Wf3[i], z);
    out[m] = 1.f / (1.f + expf(-z));
}

// ---------------------------------------------------------------------------
// Host launcher
// ---------------------------------------------------------------------------
static inline dim3 grid_for(int threads) { return dim3((threads + 255) / 256); }

extern "C" void kernel_launch(void* const* d_in, const int* in_sizes, int n_in,
                              void* d_out, int out_size, void* d_ws, size_t ws_size,
                              hipStream_t stream)
{
    (void)in_sizes; (void)n_in; (void)out_size; (void)ws_size;

    const float* one_hot  = (const float*)d_in[0];
    const float* features = (const float*)d_in[1];
    // d_in[2] = gemme_features: unused by the reference.
    const float* A    = (const float*)d_in[3];
    const float* We1  = (const float*)d_in[4];  const float* be1 = (const float*)d_in[5];
    const float* We2  = (const float*)d_in[6];  const float* be2 = (const float*)d_in[7];
    const float* We3  = (const float*)d_in[8];  const float* be3 = (const float*)d_in[9];
    const float* Wg1  = (const float*)d_in[10]; const float* bg1 = (const float*)d_in[11];
    const float* Wg2  = (const float*)d_in[12]; const float* bg2 = (const float*)d_in[13];
    const float* Wg3  = (const float*)d_in[14]; const float* bg3 = (const float*)d_in[15];
    const float* Wg4  = (const float*)d_in[16]; const float* bg4 = (const float*)d_in[17];
    const float* Wg5  = (const float*)d_in[18]; const float* bg5 = (const float*)d_in[19];
    const float* Wf1  = (const float*)d_in[20]; const float* bf1 = (const float*)d_in[21];
    const float* Wf2  = (const float*)d_in[22]; const float* bf2 = (const float*)d_in[23];
    const float* Wf3  = (const float*)d_in[24]; const float* bf3 = (const float*)d_in[25];
    float* out = (float*)d_out;

    // Workspace layout (floats): bufA[N*128] bufB[N*128] hb[N*64] part[16*N*64]
    // total = N*1344 floats = 66 MB (ws is ~2.4 GB per round-1 poison-fill size)
    float* bufA = (float*)d_ws;
    float* bufB = bufA + (size_t)NROWS * 128;
    float* hb   = bufB + (size_t)NROWS * 128;
    float* part = hb   + (size_t)NROWS * 64;

    const dim3 agrid(48 * 16);   // MT(48) x SPLIT(16)

    // Encoder
    enc1_kernel<<<grid_for(NROWS * 8), 256, 0, stream>>>(one_hot, features, We1, be1, bufB);
    linear4_kernel<32, 64, true, true><<<grid_for(NROWS * 16), 256, 0, stream>>>(bufB, We2, be2, bufA);
    linear4_kernel<64, 128, true, true><<<grid_for(NROWS * 32), 256, 0, stream>>>(bufA, We3, be3, bufB);

    // gconv 1: 128 -> 64
    linear4_kernel<128, 64, false, false><<<grid_for(NROWS * 16), 256, 0, stream>>>(bufB, Wg1, nullptr, hb);
    agg_kernel<64, 8, 8><<<agrid, 256, 0, stream>>>(A, hb, part);
    reduce_kernel<64, 16><<<grid_for(NROWS * 16), 256, 0, stream>>>(part, bg1, bufA);

    // gconv 2: 64 -> 32
    linear4_kernel<64, 32, false, false><<<grid_for(NROWS * 8), 256, 0, stream>>>(bufA, Wg2, nullptr, hb);
    agg_kernel<32, 8, 4><<<agrid, 256, 0, stream>>>(A, hb, part);
    reduce_kernel<32, 16><<<grid_for(NROWS * 8), 256, 0, stream>>>(part, bg2, bufB);

    // gconv 3: 32 -> 16
    linear4_kernel<32, 16, false, false><<<grid_for(NROWS * 4), 256, 0, stream>>>(bufB, Wg3, nullptr, hb);
    agg_kernel<16, 8, 2><<<agrid, 256, 0, stream>>>(A, hb, part);
    reduce_kernel<16, 16><<<grid_for(NROWS * 4), 256, 0, stream>>>(part, bg3, bufA);

    // gconv 4: 16 -> 8
    linear4_kernel<16, 8, false, false><<<grid_for(NROWS * 2), 256, 0, stream>>>(bufA, Wg4, nullptr, hb);
    agg_kernel<8, 8, 1><<<agrid, 256, 0, stream>>>(A, hb, part);
    reduce_kernel<8, 16><<<grid_for(NROWS * 2), 256, 0, stream>>>(part, bg4, bufB);

    // gconv 5: 8 -> 4 (+ fused final MLP + sigmoid)
    linear4_kernel<8, 4, false, false><<<grid_for(NROWS), 256, 0, stream>>>(bufB, Wg5, nullptr, hb);
    agg_kernel<4, 4, 1><<<agrid, 256, 0, stream>>>(A, hb, part);
    reduce5_final_kernel<<<grid_for(NROWS), 256, 0, stream>>>(part, bg5, Wf1, bf1, Wf2, bf2, Wf3, bf3, out);
}